// Round 9
// baseline (86.383 us; speedup 1.0000x reference)
//
#include <hip/hip_runtime.h>
#include <math.h>

#define C_FINE   100
#define C_MID    20
#define C_COARSE 5
#define D        128
#define NROWS    262144
#define NPAIRS   4950   // 100*99/2
#define NBLK4    78     // ceil(4950/64)

#define NB       512              // kMF blocks (512 thr = 8 waves; 2 blocks/CU)
#define ROWS_PB  (NROWS/NB)       // 512 rows per block
#define NSTEP    (ROWS_PB/32)     // 16 K-steps of 32 rows
#define MT       7                // 112 padded classes / 16
#define PSTR2    (113*128)        // per-block partial: [112][128] sums + [128] cnt row

// ws layout in floats
#define FP_OFF    0        // fine protos [100][128]
#define DM_OFF    12800    // mid dist table [20][20]
#define DC_OFF    13200    // coarse dist table [5][5]
#define ACC_OFF   13232    // 5 doubles (byte 52928, 8-aligned)
#define DONE_OFF  13244    // int completion counter
#define CNT_OFF   13248    // class counts [100] (float), padded to 128
#define FSUM_OFF  13376    // fine sums [100][128]
#define PART_OFF  26176    // partials: NB x PSTR2  (~29.7 MB)

typedef __attribute__((ext_vector_type(8))) short bf16x8;   // 8 bf16 (4 VGPRs)
typedef __attribute__((ext_vector_type(4))) float f32x4;    // MFMA C/D

static __device__ __forceinline__ unsigned short f2bf(float f) {
    unsigned int x = __float_as_uint(f);
    x += 0x7FFF + ((x >> 16) & 1);      // round-to-nearest-even
    return (unsigned short)(x >> 16);
}

// ---------------- kMF: one-hot MFMA segment-sum, LDS-staged streaming ----------------
// Same verified fragment mapping as R8 (absmax 0.0):
// A lane l: m=l&15, k=8*(l>>4)+j ; B lane l: n=l&15(col), k=8*(l>>4)+j ;
// C/D lane l: col=l&15, row=4*(l>>4)+i.
// New data path: float4 global loads -> LDS tile (double-buffered, T14
// issue-early/write-late) -> ds_read fragments. 8 waves, wave w owns cols
// [16w,16w+16). One barrier per 32-row step.
__global__ __launch_bounds__(512, 4) void kMF(const float* __restrict__ rep,
                                              const int* __restrict__ tgt,
                                              float* __restrict__ ws) {
    __shared__ float tile[2][32 * 128];   // 2 x 16 KB
    __shared__ int   ltgt[ROWS_PB];       // 2 KB
    __shared__ int   hist[128];
    const int t  = threadIdx.x;
    const int w  = t >> 6;        // wave 0..7: cols [16w, 16w+16)
    const int l  = t & 63;
    const int lg = l >> 4;        // k-group 0..3
    const int ll = l & 15;
    const int blk   = blockIdx.x;
    const int rbase = blk * ROWS_PB;

    if (t < 128) hist[t] = 0;
    __syncthreads();
    {
        int c = tgt[rbase + t];   // one row per thread
        ltgt[t] = c;
        atomicAdd(&hist[c], 1);
    }

    const float4* rep4 = (const float4*)rep;
    const int tile4base = rbase * (D / 4);     // float4 index of block start

    f32x4 acc[MT];
    #pragma unroll
    for (int m = 0; m < MT; ++m)
        #pragma unroll
        for (int i = 0; i < 4; ++i) acc[m][i] = 0.f;

    // prologue: stage step 0 (2 float4 per thread = 16 KB tile)
    {
        float4 a0 = rep4[tile4base + t];
        float4 a1 = rep4[tile4base + 512 + t];
        ((float4*)tile[0])[t]       = a0;
        ((float4*)tile[0])[t + 512] = a1;
    }
    __syncthreads();   // also publishes ltgt/hist

    #pragma unroll 1
    for (int s = 0; s < NSTEP; ++s) {
        const int buf = s & 1;
        float4 na, nb;
        if (s + 1 < NSTEP) {                       // issue next-step loads EARLY
            na = rep4[tile4base + (s + 1) * 1024 + t];
            nb = rep4[tile4base + (s + 1) * 1024 + 512 + t];
        }

        // ---- compute step s from tile[buf] ----
        const float* tf = tile[buf];
        float vB[8];
        int   tv[8];
        #pragma unroll
        for (int j = 0; j < 8; ++j) {
            vB[j] = tf[(8 * lg + j) * D + 16 * w + ll];
            tv[j] = ltgt[s * 32 + 8 * lg + j];
        }
        bf16x8 b0;
        #pragma unroll
        for (int j = 0; j < 8; ++j) b0[j] = (short)f2bf(vB[j]);
        #pragma unroll
        for (int m = 0; m < MT; ++m) {
            const int cb = 16 * m + ll;
            bf16x8 a;
            #pragma unroll
            for (int j = 0; j < 8; ++j)
                a[j] = (tv[j] == cb) ? (short)0x3F80 : (short)0;
            acc[m] = __builtin_amdgcn_mfma_f32_16x16x32_bf16(a, b0, acc[m], 0, 0, 0);
        }

        if (s + 1 < NSTEP) {                       // write-late (vmcnt waits here)
            ((float4*)tile[buf ^ 1])[t]       = na;
            ((float4*)tile[buf ^ 1])[t + 512] = nb;
        }
        __syncthreads();
    }

    float* part = ws + PART_OFF + (size_t)blk * PSTR2;
    #pragma unroll
    for (int m = 0; m < MT; ++m)
        #pragma unroll
        for (int i = 0; i < 4; ++i)
            part[(16 * m + 4 * lg + i) * D + 16 * w + ll] = acc[m][i];
    if (t < 128) part[112 * D + t] = (t < C_FINE) ? (float)hist[t] : 0.f;
}

// ---------------- kRed: merge NB partials -> FSUM + CNT (no atomics) ----------------
__global__ __launch_bounds__(512) void kRed(float* __restrict__ ws) {
    const int c = blockIdx.x;            // class 0..99
    const int t = threadIdx.x;
    const int g = t >> 7, d = t & 127;
    float s = 0.f;
    #pragma unroll 8
    for (int b = g; b < NB; b += 4)
        s += ws[PART_OFF + (size_t)b * PSTR2 + c * D + d];
    __shared__ float red[4][128];
    red[g][d] = s;

    float cv = ws[PART_OFF + (size_t)t * PSTR2 + 112 * D + c];   // t < NB == 512
    #pragma unroll
    for (int off = 32; off > 0; off >>= 1) cv += __shfl_down(cv, off);
    __shared__ float cw[8];
    if ((t & 63) == 0) cw[t >> 6] = cv;
    __syncthreads();
    if (g == 0) ws[FSUM_OFF + c * D + d] = red[0][d] + red[1][d] + red[2][d] + red[3][d];
    if (t == 0) {
        float tot = 0.f;
        #pragma unroll
        for (int q = 0; q < 8; ++q) tot += cw[q];
        ws[CNT_OFF + c] = tot;
    }
}

// ---------------- k3: normalize + hierarchy + distance tables (all in LDS) ----------------
__global__ __launch_bounds__(256) void k3_hier(const int* __restrict__ f2m,
                                               const int* __restrict__ f2c,
                                               float* __restrict__ ws) {
    __shared__ float fineP[C_FINE][D];        // 51.2 KB
    __shared__ float midP[C_MID][D + 1];
    __shared__ float coarP[C_COARSE][D + 1];
    __shared__ int   sf2m[C_FINE], sf2c[C_FINE], m2c[C_MID];
    __shared__ float midCnt[C_MID], coarCnt[C_COARSE];
    __shared__ float sTot[C_FINE];
    const int t = threadIdx.x;

    if (t < C_FINE) {
        sf2m[t] = f2m[t]; sf2c[t] = f2c[t];
        sTot[t] = ws[CNT_OFF + t];
    }
    for (int e = t; e < C_MID * (D + 1); e += 256) ((float*)midP)[e] = 0.f;
    for (int e = t; e < C_COARSE * (D + 1); e += 256) ((float*)coarP)[e] = 0.f;
    __syncthreads();

    for (int e = t; e < C_FINE * D; e += 256) {
        int c = e >> 7, d = e & 127;
        float v = ws[FSUM_OFF + e] / fmaxf(sTot[c], 1.f);
        fineP[c][d] = v;
        ws[FP_OFF + e] = v;
    }
    if (t < C_MID) {
        int cntv = 0, mx = -2147483647;
        for (int f = 0; f < C_FINE; ++f)
            if (sf2m[f] == t) { ++cntv; mx = max(mx, sf2c[f]); }
        midCnt[t] = (float)max(cntv, 1);
        m2c[t] = mx;
    }
    __syncthreads();

    if (t < D) {
        const int d = t;
        for (int f = 0; f < C_FINE; ++f)
            midP[sf2m[f]][d] += fineP[f][d];
        for (int m = 0; m < C_MID; ++m)
            midP[m][d] /= midCnt[m];
    }
    if (t >= 128 && t < 128 + C_COARSE) {
        int cc = t - 128, cntv = 0;
        for (int m = 0; m < C_MID; ++m) if (m2c[m] == cc) ++cntv;
        coarCnt[cc] = (float)max(cntv, 1);
    }
    __syncthreads();

    if (t < D) {
        const int d = t;
        for (int m = 0; m < C_MID; ++m)
            coarP[m2c[m]][d] += midP[m][d];
        for (int cc = 0; cc < C_COARSE; ++cc)
            coarP[cc][d] /= coarCnt[cc];
    }
    __syncthreads();

    for (int e = t; e < C_MID * C_MID; e += 256) {
        int m1 = e / C_MID, m2 = e % C_MID;
        float ss = 0.f;
        #pragma unroll 8
        for (int d = 0; d < D; ++d) {
            float df = midP[m1][d] - midP[m2][d];
            ss += df * df;
        }
        ws[DM_OFF + e] = sqrtf(ss + 1e-12f);
    }
    for (int e = t; e < C_COARSE * C_COARSE; e += 256) {
        int c1 = e / C_COARSE, c2 = e % C_COARSE;
        float ss = 0.f;
        #pragma unroll 8
        for (int d = 0; d < D; ++d) {
            float df = coarP[c1][d] - coarP[c2][d];
            ss += df * df;
        }
        ws[DC_OFF + e] = sqrtf(ss + 1e-12f);
    }
    if (t < 5) ((double*)(ws + ACC_OFF))[t] = 0.0;   // zero moment accumulators
    if (t == 5) ((int*)ws + DONE_OFF)[0] = 0;        // zero completion counter
}

// ---------------- k45: all fine pairs -> moments, last block finalizes ----------------
__global__ __launch_bounds__(64) void k45_pairs(float* __restrict__ ws,
                                                const int* __restrict__ f2m,
                                                const int* __restrict__ f2c,
                                                float* __restrict__ out) {
    const int p = blockIdx.x * 64 + threadIdx.x;
    double st = 0, sp = 0, stp = 0, stt = 0, spp = 0;
    if (p < NPAIRS) {
        int i = 0, rem = p;
        while (rem >= C_FINE - 1 - i) { rem -= C_FINE - 1 - i; ++i; }
        int j = i + 1 + rem;

        const float4* Fi = (const float4*)(ws + FP_OFF + i * D);
        const float4* Fj = (const float4*)(ws + FP_OFF + j * D);
        float ss = 0.f;
        #pragma unroll
        for (int k = 0; k < D / 4; ++k) {
            float4 a = Fi[k], b = Fj[k];
            float dx = a.x - b.x, dy = a.y - b.y, dz = a.z - b.z, dw = a.w - b.w;
            ss += dx * dx + dy * dy + dz * dz + dw * dw;
        }
        float proto = sqrtf(ss + 1e-12f);
        float tree  = ws[DC_OFF + f2c[i] * C_COARSE + f2c[j]]
                    + ws[DM_OFF + f2m[i] * C_MID + f2m[j]];
        st = tree; sp = proto;
        stp = (double)tree * (double)proto;
        stt = (double)tree * (double)tree;
        spp = (double)proto * (double)proto;
    }
    for (int off = 32; off > 0; off >>= 1) {
        st  += __shfl_down(st, off);
        sp  += __shfl_down(sp, off);
        stp += __shfl_down(stp, off);
        stt += __shfl_down(stt, off);
        spp += __shfl_down(spp, off);
    }
    if (threadIdx.x == 0) {
        double* acc = (double*)(ws + ACC_OFF);
        atomicAdd(&acc[0], st);
        atomicAdd(&acc[1], sp);
        atomicAdd(&acc[2], stp);
        atomicAdd(&acc[3], stt);
        atomicAdd(&acc[4], spp);
        __threadfence();
        int* done = (int*)ws + DONE_OFF;
        int ticket = atomicAdd(done, 1);
        if (ticket == NBLK4 - 1) {
            double fst  = atomicAdd(&acc[0], 0.0);
            double fsp  = atomicAdd(&acc[1], 0.0);
            double fstp = atomicAdd(&acc[2], 0.0);
            double fstt = atomicAdd(&acc[3], 0.0);
            double fspp = atomicAdd(&acc[4], 0.0);
            const double n = (double)NPAIRS;
            double num = fstp - fst * fsp / n;
            double dtt = fstt - fst * fst / n;
            double dpp = fspp - fsp * fsp / n;
            double corr = num / sqrt(dtt * dpp + 1e-12);
            out[0] = (float)(1.0 - corr);
        }
    }
}

extern "C" void kernel_launch(void* const* d_in, const int* in_sizes, int n_in,
                              void* d_out, int out_size, void* d_ws, size_t ws_size,
                              hipStream_t stream) {
    const float* rep = (const float*)d_in[0];
    const int*   tgt = (const int*)d_in[1];
    const int*   f2m = (const int*)d_in[2];
    const int*   f2c = (const int*)d_in[3];
    float* ws  = (float*)d_ws;
    float* out = (float*)d_out;

    hipLaunchKernelGGL(kMF,       dim3(NB),     dim3(512), 0, stream, rep, tgt, ws);
    hipLaunchKernelGGL(kRed,      dim3(C_FINE), dim3(512), 0, stream, ws);
    hipLaunchKernelGGL(k3_hier,   dim3(1),      dim3(256), 0, stream, f2m, f2c, ws);
    hipLaunchKernelGGL(k45_pairs, dim3(NBLK4),  dim3(64),  0, stream,
                       ws, f2m, f2c, out);
}

// Round 10
// 81.702 us; speedup vs baseline: 1.0573x; 1.0573x over previous
//
#include <hip/hip_runtime.h>
#include <math.h>

#define C_FINE   100
#define C_MID    20
#define C_COARSE 5
#define D        128
#define NROWS    262144
#define NPAIRS   4950   // 100*99/2
#define NBLK4    78     // ceil(4950/64)

#define NB       512              // kMF blocks (512 thr = 8 waves)
#define ROWS_PB  (NROWS/NB)       // 512 rows per block
#define NSTEP    (ROWS_PB/32)     // 16 K-steps of 32 rows
#define MT       7                // 112 padded classes / 16
#define PSTR2    (113*128)        // per-block partial: [112][128] sums + [128] cnt row

// ws layout in floats
#define FP_OFF    0        // fine protos [100][128]
#define DM_OFF    12800    // mid dist table [20][20]
#define DC_OFF    13200    // coarse dist table [5][5]
#define ACC_OFF   13232    // 5 doubles (byte 52928, 8-aligned)
#define DONE_OFF  13244    // int completion counter
#define CNT_OFF   13248    // class counts [100] (float), padded to 128
#define FSUM_OFF  13376    // fine sums [100][128]
#define PART_OFF  26176    // partials: NB x PSTR2  (~29.7 MB)

typedef __attribute__((ext_vector_type(8))) short bf16x8;   // 8 bf16 (4 VGPRs)
typedef __attribute__((ext_vector_type(4))) float f32x4;    // MFMA C/D

static __device__ __forceinline__ unsigned short f2bf(float f) {
    unsigned int x = __float_as_uint(f);
    x += 0x7FFF + ((x >> 16) & 1);      // round-to-nearest-even
    return (unsigned short)(x >> 16);
}

// ---------------- kMF: one-hot MFMA segment-sum, sparse LDS A-image ----------------
// Verified fragment mapping (R8/R9, absmax 0.0):
//   A lane l: m-row = l&15 (+16*mt), k = 8*(l>>4)+j
//   B lane l: n-col = l&15 (+16w),   k = 8*(l>>4)+j
//   C/D lane l: col = l&15, row = 4*(l>>4)+i
// A is 99% zeros -> keep a [112][32] bf16 LDS image per buffer; per step only
// 32 set-writes (1.0 at [tgt[k]][k]) + 32 re-zero writes of the step-2-ago ones.
// All 8 waves share the image via ds_read_b128 (8x dedup of the old VALU build).
__global__ __launch_bounds__(512, 4) void kMF(const float* __restrict__ rep,
                                              const int* __restrict__ tgt,
                                              float* __restrict__ ws) {
    __shared__ float tile[2][32 * 128];    // 2 x 16 KB, XOR-swizzled f4 layout
    __shared__ short Aimg[2][112 * 32];    // 2 x 7 KB one-hot bf16 image
    __shared__ int   ltgt[ROWS_PB];        // 2 KB
    __shared__ int   hist[128];
    const int t  = threadIdx.x;
    const int w  = t >> 6;        // wave 0..7: cols [16w, 16w+16)
    const int l  = t & 63;
    const int lg = l >> 4;        // k-group 0..3
    const int ll = l & 15;
    const int blk   = blockIdx.x;
    const int rbase = blk * ROWS_PB;

    if (t < 128) hist[t] = 0;
    __syncthreads();

    const float4* rep4 = (const float4*)rep;
    const int tile4base = rbase * (D / 4);

    // prologue: tgt -> ltgt + hist, zero A images, stage tile 0
    const int myc = tgt[rbase + t];        // one row per thread
    ltgt[t] = myc;
    atomicAdd(&hist[myc], 1);
    for (int e = t; e < 2 * 112 * 32 / 2; e += 512) ((int*)Aimg)[e] = 0;
    {
        // swizzled store: f4idx = row*32 + (d4 ^ ((row>>3)&3))
        float4 a0 = rep4[tile4base + t];         // row0 = t>>5 (0..15), d4 = t&31
        float4 a1 = rep4[tile4base + 512 + t];   // row1 = 16 + (t>>5)
        const int r0 = t >> 5, d4 = t & 31;
        const int r1 = 16 + r0;
        ((float4*)tile[0])[r0 * 32 + (d4 ^ ((r0 >> 3) & 3))] = a0;
        ((float4*)tile[0])[r1 * 32 + (d4 ^ ((r1 >> 3) & 3))] = a1;
    }
    __syncthreads();                        // zeros + ltgt visible
    if (t < 32) Aimg[0][myc * 32 + t] = (short)0x3F80;   // step-0 ones (own row)
    __syncthreads();

    f32x4 acc[MT];
    #pragma unroll
    for (int m = 0; m < MT; ++m)
        #pragma unroll
        for (int i = 0; i < 4; ++i) acc[m][i] = 0.f;

    // B read base: float-off = lg*8*128 + (d4^lg)*4 + (ll&3), d4 = 4w + (ll>>2)
    const int d4r = 4 * w + (ll >> 2);
    const int bB  = lg * 1024 + ((d4r ^ lg) << 2) + (ll & 3);

    #pragma unroll 1
    for (int s = 0; s < NSTEP; ++s) {
        const int buf = s & 1;
        float4 na, nb;
        if (s + 1 < NSTEP) {                     // issue next-step loads EARLY
            na = rep4[tile4base + (s + 1) * 1024 + t];
            nb = rep4[tile4base + (s + 1) * 1024 + 512 + t];
        }

        // ---- compute step s ----
        const float* tf = tile[buf];
        bf16x8 b0;
        #pragma unroll
        for (int j = 0; j < 8; ++j) b0[j] = (short)f2bf(tf[bB + j * 128]);

        const short* Ab = Aimg[buf];
        bf16x8 af[MT];
        #pragma unroll
        for (int m = 0; m < MT; ++m)
            af[m] = *(const bf16x8*)&Ab[(16 * m + ll) * 32 + 8 * lg];
        #pragma unroll
        for (int m = 0; m < MT; ++m)
            acc[m] = __builtin_amdgcn_mfma_f32_16x16x32_bf16(af[m], b0, acc[m], 0, 0, 0);

        // ---- maintain A[buf^1]: zero step s-1 ones, set step s+1 ones ----
        // (buf^1 was read at s-1, next read at s+1 -> no concurrent access;
        //  zero-then-set per column t by the SAME thread -> DS in-order safe)
        if (t < 32) {
            short* An = (short*)Aimg[buf ^ 1];
            if (s >= 1)        An[ltgt[(s - 1) * 32 + t] * 32 + t] = 0;
            if (s + 1 < NSTEP) An[ltgt[(s + 1) * 32 + t] * 32 + t] = (short)0x3F80;
        }
        if (s + 1 < NSTEP) {                     // write-late (vmcnt waits here)
            const int r0 = t >> 5, d4 = t & 31;
            const int r1 = 16 + r0;
            ((float4*)tile[buf ^ 1])[r0 * 32 + (d4 ^ ((r0 >> 3) & 3))] = na;
            ((float4*)tile[buf ^ 1])[r1 * 32 + (d4 ^ ((r1 >> 3) & 3))] = nb;
        }
        __syncthreads();
    }

    float* part = ws + PART_OFF + (size_t)blk * PSTR2;
    #pragma unroll
    for (int m = 0; m < MT; ++m)
        #pragma unroll
        for (int i = 0; i < 4; ++i)
            part[(16 * m + 4 * lg + i) * D + 16 * w + ll] = acc[m][i];
    if (t < 128) part[112 * D + t] = (t < C_FINE) ? (float)hist[t] : 0.f;
}

// ---------------- kRed: merge NB partials -> FSUM + CNT (no atomics) ----------------
__global__ __launch_bounds__(512) void kRed(float* __restrict__ ws) {
    const int c = blockIdx.x;            // class 0..99
    const int t = threadIdx.x;
    const int g = t >> 7, d = t & 127;
    float s = 0.f;
    #pragma unroll 8
    for (int b = g; b < NB; b += 4)
        s += ws[PART_OFF + (size_t)b * PSTR2 + c * D + d];
    __shared__ float red[4][128];
    red[g][d] = s;

    float cv = ws[PART_OFF + (size_t)t * PSTR2 + 112 * D + c];   // t < NB == 512
    #pragma unroll
    for (int off = 32; off > 0; off >>= 1) cv += __shfl_down(cv, off);
    __shared__ float cw[8];
    if ((t & 63) == 0) cw[t >> 6] = cv;
    __syncthreads();
    if (g == 0) ws[FSUM_OFF + c * D + d] = red[0][d] + red[1][d] + red[2][d] + red[3][d];
    if (t == 0) {
        float tot = 0.f;
        #pragma unroll
        for (int q = 0; q < 8; ++q) tot += cw[q];
        ws[CNT_OFF + c] = tot;
    }
}

// ---------------- k3: normalize + hierarchy + distance tables (all in LDS) ----------------
__global__ __launch_bounds__(256) void k3_hier(const int* __restrict__ f2m,
                                               const int* __restrict__ f2c,
                                               float* __restrict__ ws) {
    __shared__ float fineP[C_FINE][D];        // 51.2 KB
    __shared__ float midP[C_MID][D + 1];
    __shared__ float coarP[C_COARSE][D + 1];
    __shared__ int   sf2m[C_FINE], sf2c[C_FINE], m2c[C_MID];
    __shared__ float midCnt[C_MID], coarCnt[C_COARSE];
    __shared__ float sTot[C_FINE];
    const int t = threadIdx.x;

    if (t < C_FINE) {
        sf2m[t] = f2m[t]; sf2c[t] = f2c[t];
        sTot[t] = ws[CNT_OFF + t];
    }
    for (int e = t; e < C_MID * (D + 1); e += 256) ((float*)midP)[e] = 0.f;
    for (int e = t; e < C_COARSE * (D + 1); e += 256) ((float*)coarP)[e] = 0.f;
    __syncthreads();

    for (int e = t; e < C_FINE * D; e += 256) {
        int c = e >> 7, d = e & 127;
        float v = ws[FSUM_OFF + e] / fmaxf(sTot[c], 1.f);
        fineP[c][d] = v;
        ws[FP_OFF + e] = v;
    }
    if (t < C_MID) {
        int cntv = 0, mx = -2147483647;
        for (int f = 0; f < C_FINE; ++f)
            if (sf2m[f] == t) { ++cntv; mx = max(mx, sf2c[f]); }
        midCnt[t] = (float)max(cntv, 1);
        m2c[t] = mx;
    }
    __syncthreads();

    if (t < D) {
        const int d = t;
        for (int f = 0; f < C_FINE; ++f)
            midP[sf2m[f]][d] += fineP[f][d];
        for (int m = 0; m < C_MID; ++m)
            midP[m][d] /= midCnt[m];
    }
    if (t >= 128 && t < 128 + C_COARSE) {
        int cc = t - 128, cntv = 0;
        for (int m = 0; m < C_MID; ++m) if (m2c[m] == cc) ++cntv;
        coarCnt[cc] = (float)max(cntv, 1);
    }
    __syncthreads();

    if (t < D) {
        const int d = t;
        for (int m = 0; m < C_MID; ++m)
            coarP[m2c[m]][d] += midP[m][d];
        for (int cc = 0; cc < C_COARSE; ++cc)
            coarP[cc][d] /= coarCnt[cc];
    }
    __syncthreads();

    for (int e = t; e < C_MID * C_MID; e += 256) {
        int m1 = e / C_MID, m2 = e % C_MID;
        float ss = 0.f;
        #pragma unroll 8
        for (int d = 0; d < D; ++d) {
            float df = midP[m1][d] - midP[m2][d];
            ss += df * df;
        }
        ws[DM_OFF + e] = sqrtf(ss + 1e-12f);
    }
    for (int e = t; e < C_COARSE * C_COARSE; e += 256) {
        int c1 = e / C_COARSE, c2 = e % C_COARSE;
        float ss = 0.f;
        #pragma unroll 8
        for (int d = 0; d < D; ++d) {
            float df = coarP[c1][d] - coarP[c2][d];
            ss += df * df;
        }
        ws[DC_OFF + e] = sqrtf(ss + 1e-12f);
    }
    if (t < 5) ((double*)(ws + ACC_OFF))[t] = 0.0;   // zero moment accumulators
    if (t == 5) ((int*)ws + DONE_OFF)[0] = 0;        // zero completion counter
}

// ---------------- k45: all fine pairs -> moments, last block finalizes ----------------
__global__ __launch_bounds__(64) void k45_pairs(float* __restrict__ ws,
                                                const int* __restrict__ f2m,
                                                const int* __restrict__ f2c,
                                                float* __restrict__ out) {
    const int p = blockIdx.x * 64 + threadIdx.x;
    double st = 0, sp = 0, stp = 0, stt = 0, spp = 0;
    if (p < NPAIRS) {
        int i = 0, rem = p;
        while (rem >= C_FINE - 1 - i) { rem -= C_FINE - 1 - i; ++i; }
        int j = i + 1 + rem;

        const float4* Fi = (const float4*)(ws + FP_OFF + i * D);
        const float4* Fj = (const float4*)(ws + FP_OFF + j * D);
        float ss = 0.f;
        #pragma unroll
        for (int k = 0; k < D / 4; ++k) {
            float4 a = Fi[k], b = Fj[k];
            float dx = a.x - b.x, dy = a.y - b.y, dz = a.z - b.z, dw = a.w - b.w;
            ss += dx * dx + dy * dy + dz * dz + dw * dw;
        }
        float proto = sqrtf(ss + 1e-12f);
        float tree  = ws[DC_OFF + f2c[i] * C_COARSE + f2c[j]]
                    + ws[DM_OFF + f2m[i] * C_MID + f2m[j]];
        st = tree; sp = proto;
        stp = (double)tree * (double)proto;
        stt = (double)tree * (double)tree;
        spp = (double)proto * (double)proto;
    }
    for (int off = 32; off > 0; off >>= 1) {
        st  += __shfl_down(st, off);
        sp  += __shfl_down(sp, off);
        stp += __shfl_down(stp, off);
        stt += __shfl_down(stt, off);
        spp += __shfl_down(spp, off);
    }
    if (threadIdx.x == 0) {
        double* acc = (double*)(ws + ACC_OFF);
        atomicAdd(&acc[0], st);
        atomicAdd(&acc[1], sp);
        atomicAdd(&acc[2], stp);
        atomicAdd(&acc[3], stt);
        atomicAdd(&acc[4], spp);
        __threadfence();
        int* done = (int*)ws + DONE_OFF;
        int ticket = atomicAdd(done, 1);
        if (ticket == NBLK4 - 1) {
            double fst  = atomicAdd(&acc[0], 0.0);
            double fsp  = atomicAdd(&acc[1], 0.0);
            double fstp = atomicAdd(&acc[2], 0.0);
            double fstt = atomicAdd(&acc[3], 0.0);
            double fspp = atomicAdd(&acc[4], 0.0);
            const double n = (double)NPAIRS;
            double num = fstp - fst * fsp / n;
            double dtt = fstt - fst * fst / n;
            double dpp = fspp - fsp * fsp / n;
            double corr = num / sqrt(dtt * dpp + 1e-12);
            out[0] = (float)(1.0 - corr);
        }
    }
}

extern "C" void kernel_launch(void* const* d_in, const int* in_sizes, int n_in,
                              void* d_out, int out_size, void* d_ws, size_t ws_size,
                              hipStream_t stream) {
    const float* rep = (const float*)d_in[0];
    const int*   tgt = (const int*)d_in[1];
    const int*   f2m = (const int*)d_in[2];
    const int*   f2c = (const int*)d_in[3];
    float* ws  = (float*)d_ws;
    float* out = (float*)d_out;

    hipLaunchKernelGGL(kMF,       dim3(NB),     dim3(512), 0, stream, rep, tgt, ws);
    hipLaunchKernelGGL(kRed,      dim3(C_FINE), dim3(512), 0, stream, ws);
    hipLaunchKernelGGL(k3_hier,   dim3(1),      dim3(256), 0, stream, f2m, f2c, ws);
    hipLaunchKernelGGL(k45_pairs, dim3(NBLK4),  dim3(64),  0, stream,
                       ws, f2m, f2c, out);
}